// Round 13
// baseline (67.862 us; speedup 1.0000x reference)
//
#include <hip/hip_runtime.h>

typedef __bf16 bf16x8 __attribute__((ext_vector_type(8)));
typedef float f32x4 __attribute__((ext_vector_type(4)));
typedef unsigned int uint;

#define XA_STR 152   // shorts; 304B rows, 16B-aligned

union Frag { __bf16 b[8]; bf16x8 v; unsigned short u[8]; };

__device__ __forceinline__ unsigned short bfbits(float f) {
  union { __bf16 h; unsigned short s; } c; c.h = (__bf16)f; return c.s;
}
__device__ __forceinline__ float bf2f(unsigned short h) {
  return __uint_as_float(((uint)h) << 16);
}

#define GL1(dst, voff, base, IMM) \
  asm volatile("global_load_dword %0, %1, %2 offset:" #IMM : "=v"(dst) : "v"(voff), "s"(base))
#define GL4(dst, voff, base) \
  asm volatile("global_load_dwordx4 %0, %1, %2" : "=v"(dst) : "v"(voff), "s"(base))
#define WAITV(N) do { asm volatile("s_waitcnt vmcnt(" #N ")" ::: "memory"); \
  __builtin_amdgcn_sched_barrier(0); } while (0)
#define BARX() asm volatile("s_waitcnt lgkmcnt(0)\n\ts_barrier" ::: "memory")

// Block = (slot s, E-quarter q): 512 threads = 8 waves; wave owns 16 weight
// cols. Wave-private weight staging (R12 structure, unchanged): each wave
// global_load_lds's its own 2KB slice into a private 3-slot LDS ring,
// wave-local counted-vmcnt ladder, no mid-stream barriers.
// GATHER=1: X gathered directly from fp32 x[b][f][s] (asm-pinned strided
// loads hidden under the weight prologue). GATHER=0: X from bf16 staged
// Xt[s][b][f].
template <int GATHER>
__global__ __launch_bounds__(512, 4) void mlp_main(
    const void* __restrict__ Xin,
    const float* __restrict__ Wu, const float* __restrict__ bu,
    const float* __restrict__ Wg, const float* __restrict__ bg,
    const float* __restrict__ Wd,
    unsigned short* __restrict__ partial)    // [512][64][128] bf16
{
  const int bid = blockIdx.x;
  const int s = bid >> 2, q = bid & 3;
  const int tid = threadIdx.x;
  const int wv = tid >> 6, lane = tid & 63;
  const int l16 = lane & 15, lg = lane >> 4;
  const int col = wv * 16 + l16;

  __shared__ __align__(16) float wsl[8][3][512];           // 48KB: per-wave ring
  __shared__ __align__(16) unsigned short xa[64 * XA_STR]; // X then A2 (19KB)

  const float* WuS = Wu + (size_t)s * 65536 + q * 128 + wv * 16;  // rows: 512f
  const float* WgS = Wg + (size_t)s * 65536 + q * 128 + wv * 16;
  const float* WdS = Wd + (size_t)s * 65536 + (size_t)q * 16384 + wv * 16; // rows: 128f

  const int rlu = lg * 4096 + l16;   // lane float-offset, up/gate
  const int rld = lg * 1024 + l16;   // lane float-offset, down

  float* const WA = &wsl[wv][0][0];
  float* const WB = &wsl[wv][1][0];
  float* const WC = &wsl[wv][2][0];

  // stage one wave-private 2KB slice; j-major LDS layout word = i*64+lane
#define ISSW(BASE, RS, OFF, SLOT) do { \
  asm volatile("s_waitcnt lgkmcnt(0)" ::: "memory"); \
  __builtin_amdgcn_sched_barrier(0); \
  _Pragma("unroll") for (int i = 0; i < 8; ++i) \
    __builtin_amdgcn_global_load_lds( \
      (const __attribute__((address_space(1))) void*)((BASE) + (OFF) + i * (RS)), \
      (__attribute__((address_space(3))) void*)((SLOT) + i * 64), 4, 0, 0); \
} while (0)

#define BS(SLOT, FR) do { \
  _Pragma("unroll") for (int j = 0; j < 8; ++j) \
    FR.b[j] = (__bf16)(SLOT)[j * 64 + (lg << 4) + l16]; \
} while (0)

  Frag a[4];
#define LOADA(KK) do { \
  _Pragma("unroll") \
  for (int mt = 0; mt < 4; ++mt) \
    a[mt].v = *(const bf16x8*)&xa[(mt * 16 + l16) * XA_STR + (((KK) * 4 + lg) << 3)]; \
} while (0)

  f32x4 au[4] = {}, ag[4] = {}, ad[4] = {};
#define MFMA4(FR, ACC) do { \
  _Pragma("unroll") \
  for (int mt = 0; mt < 4; ++mt) \
    ACC[mt] = __builtin_amdgcn_mfma_f32_16x16x32_bf16(a[mt].v, FR.v, ACC[mt], 0, 0, 0); \
} while (0)

  // ---- prologue: biases + X (asm-pinned), then 3 weight slices ----
  float buv, bgv;
  const uint vbo = (uint)((q * 128 + col) * 4);
  GL1(buv, vbo, bu + s * 512, 0);
  GL1(bgv, vbo, bg + s * 512, 0);

  f32x4 xq0, xq1;
  float gx[16];
  if constexpr (GATHER) {
    // thread covers b = tid>>3, d = (tid&7)*16 .. +15; strided 512B loads
    const float* xs = (const float*)Xin;
    const uint vg  = (uint)((tid >> 3) * 65536 + (tid & 7) * 8192 + s * 4);
    const uint vg2 = vg + 4096;
    GL1(gx[0],  vg,  xs, 0);    GL1(gx[1],  vg,  xs, 512);
    GL1(gx[2],  vg,  xs, 1024); GL1(gx[3],  vg,  xs, 1536);
    GL1(gx[4],  vg,  xs, 2048); GL1(gx[5],  vg,  xs, 2560);
    GL1(gx[6],  vg,  xs, 3072); GL1(gx[7],  vg,  xs, 3584);
    GL1(gx[8],  vg2, xs, 0);    GL1(gx[9],  vg2, xs, 512);
    GL1(gx[10], vg2, xs, 1024); GL1(gx[11], vg2, xs, 1536);
    GL1(gx[12], vg2, xs, 2048); GL1(gx[13], vg2, xs, 2560);
    GL1(gx[14], vg2, xs, 3072); GL1(gx[15], vg2, xs, 3584);
  } else {
    const unsigned short* XtS = (const unsigned short*)Xin + (size_t)s * 8192;
    const uint vx0 = (uint)(tid * 16), vx1 = vx0 + 8192;
    GL4(xq0, vx0, XtS);
    GL4(xq1, vx1, XtS);
  }
  ISSW(WuS, 512, rlu, WA);               // u0
  ISSW(WgS, 512, rlu, WB);               // g0
  ISSW(WuS + 16384, 512, rlu, WC);       // u1

  WAITV(24);                             // biases + X arrived; 3 ISSWs remain
  if constexpr (GATHER) {
    const int gb = tid >> 3, gd = (tid & 7) * 16;
    unsigned short t16[16];
#pragma unroll
    for (int i = 0; i < 16; ++i) t16[i] = bfbits(gx[i]);
    *(uint4*)&xa[gb * XA_STR + gd]     = *(uint4*)&t16[0];
    *(uint4*)&xa[gb * XA_STR + gd + 8] = *(uint4*)&t16[8];
  } else {
    const int m0 = tid >> 4, ch0 = tid & 15;
    *(f32x4*)&xa[m0 * XA_STR + (ch0 << 3)] = xq0;
    const int p1 = tid + 512, m1 = p1 >> 4, ch1 = p1 & 15;
    *(f32x4*)&xa[m1 * XA_STR + (ch1 << 3)] = xq1;
  }
  BARX();                                // xa visible           [barrier 1]

  // ---- up/gate: 8 slices, wave-local ladder ----
  Frag f;
  WAITV(16); LOADA(0); BS(WA, f); ISSW(WgS + 16384, 512, rlu, WA); MFMA4(f, au);
  WAITV(16);           BS(WB, f); ISSW(WuS + 32768, 512, rlu, WB); MFMA4(f, ag);
  WAITV(16); LOADA(1); BS(WC, f); ISSW(WgS + 32768, 512, rlu, WC); MFMA4(f, au);
  WAITV(16);           BS(WA, f); ISSW(WuS + 49152, 512, rlu, WA); MFMA4(f, ag);
  WAITV(16); LOADA(2); BS(WB, f); ISSW(WgS + 49152, 512, rlu, WB); MFMA4(f, au);
  WAITV(16);           BS(WC, f); ISSW(WdS,         128, rld, WC); MFMA4(f, ag);
  WAITV(16); LOADA(3); BS(WA, f); ISSW(WdS +  4096, 128, rld, WA); MFMA4(f, au);
  WAITV(16);           BS(WB, f); ISSW(WdS +  8192, 128, rld, WB); MFMA4(f, ag);

  // ---- silu epilogue -> A2 into xa ----
  float a2v[4][4];
#pragma unroll
  for (int mt = 0; mt < 4; ++mt)
#pragma unroll
    for (int r = 0; r < 4; ++r) {
      const float uv = au[mt][r] + buv;
      const float gv = ag[mt][r] + bgv;
      a2v[mt][r] = uv * (gv / (1.f + __expf(-gv)));
    }
  BARX();                                // X reads done         [barrier 2]
#pragma unroll
  for (int mt = 0; mt < 4; ++mt)
#pragma unroll
    for (int r = 0; r < 4; ++r)
      xa[(mt * 16 + lg * 4 + r) * XA_STR + col] = bfbits(a2v[mt][r]);
  BARX();                                // A2 visible           [barrier 3]

  // ---- down: 4 slices ----
  WAITV(16); LOADA(0); BS(WC, f); ISSW(WdS + 12288, 128, rld, WC); MFMA4(f, ad);
  WAITV(16); LOADA(1); BS(WA, f); MFMA4(f, ad);
  WAITV(8);  LOADA(2); BS(WB, f); MFMA4(f, ad);
  WAITV(0);  LOADA(3); BS(WC, f); MFMA4(f, ad);

  unsigned short* po = partial + (size_t)bid * 8192;
#pragma unroll
  for (int mt = 0; mt < 4; ++mt)
#pragma unroll
    for (int r = 0; r < 4; ++r)
      po[(mt * 16 + lg * 4 + r) * 128 + col] = bfbits(ad[mt][r]);

#undef ISSW
#undef BS
#undef LOADA
#undef MFMA4
}

// Layer-1 finish, b-major, fused transpose-out -> xt2[d][b][s].
// Residual gathered directly from fp32 x[b][f][s] (L3-served).
__global__ __launch_bounds__(256) void finish1(
    const unsigned short* __restrict__ part, const float* __restrict__ x,
    const float* __restrict__ bd, const float* __restrict__ scale,
    unsigned short* __restrict__ xt2)
{
  const int b = blockIdx.x >> 2, sq = blockIdx.x & 3;
  const int wvt = threadIdx.x >> 6, lane = threadIdx.x & 63;
  const int d0 = lane * 2;
  const float sc0 = scale[d0], sc1 = scale[d0 + 1];
  __shared__ unsigned short zt[128][40];

  for (int i = 0; i < 8; ++i) {
    const int sl = i * 4 + wvt;
    const int s = sq * 32 + sl;
    float z0 = bd[s * 128 + d0]     + x[b * 16384 + d0 * 128 + s];
    float z1 = bd[s * 128 + d0 + 1] + x[b * 16384 + (d0 + 1) * 128 + s];
#pragma unroll
    for (int p = 0; p < 4; ++p) {
      const uint rp = *(const uint*)(part + ((size_t)(s * 4 + p)) * 8192 + b * 128 + d0);
      z0 += bf2f((unsigned short)rp);
      z1 += bf2f((unsigned short)(rp >> 16));
    }
    float ss = z0 * z0 + z1 * z1;
#pragma unroll
    for (int off = 32; off; off >>= 1) ss += __shfl_xor(ss, off);
    const float inv = rsqrtf(ss * (1.f / 128.f) + 1e-5f);
    zt[d0][sl]     = bfbits(z0 * inv * sc0);
    zt[d0 + 1][sl] = bfbits(z1 * inv * sc1);
  }
  __syncthreads();
  const int dd = threadIdx.x >> 1, so = (threadIdx.x & 1) * 16;
  unsigned short* dst = xt2 + (size_t)dd * 8192 + b * 128 + sq * 32 + so;
  const uint4* srcv = (const uint4*)&zt[dd][so];
  ((uint4*)dst)[0] = srcv[0];
  ((uint4*)dst)[1] = srcv[1];
}

// Layer-2 finish, b-major: writes out[b][t][j] fp32 coalesced.
__global__ __launch_bounds__(256) void finish2(
    const unsigned short* __restrict__ part, const unsigned short* __restrict__ xt2,
    const float* __restrict__ bd, const float* __restrict__ scale,
    float* __restrict__ out)
{
  const int b = blockIdx.x >> 2, sq = blockIdx.x & 3;
  const int wvt = threadIdx.x >> 6, lane = threadIdx.x & 63;
  const int d0 = lane * 2;
  const float sc0 = scale[d0], sc1 = scale[d0 + 1];
  for (int i = 0; i < 8; ++i) {
    const int s = sq * 32 + i * 4 + wvt;
    const uint rx = *(const uint*)(xt2 + (size_t)s * 8192 + b * 128 + d0);
    float z0 = bd[s * 128 + d0]     + bf2f((unsigned short)rx);
    float z1 = bd[s * 128 + d0 + 1] + bf2f((unsigned short)(rx >> 16));
#pragma unroll
    for (int p = 0; p < 4; ++p) {
      const uint rp = *(const uint*)(part + ((size_t)(s * 4 + p)) * 8192 + b * 128 + d0);
      z0 += bf2f((unsigned short)rp);
      z1 += bf2f((unsigned short)(rp >> 16));
    }
    float ss = z0 * z0 + z1 * z1;
#pragma unroll
    for (int off = 32; off; off >>= 1) ss += __shfl_xor(ss, off);
    const float inv = rsqrtf(ss * (1.f / 128.f) + 1e-5f);
    *(float2*)(out + (size_t)b * 16384 + s * 128 + d0) =
        make_float2(z0 * inv * sc0, z1 * inv * sc1);
  }
}

extern "C" void kernel_launch(void* const* d_in, const int* in_sizes, int n_in,
                              void* d_out, int out_size, void* d_ws, size_t ws_size,
                              hipStream_t stream) {
  (void)in_sizes; (void)n_in; (void)out_size; (void)ws_size;
  const float* x   = (const float*)d_in[0];
  const float* W1u = (const float*)d_in[1];
  const float* b1u = (const float*)d_in[2];
  const float* W1g = (const float*)d_in[3];
  const float* b1g = (const float*)d_in[4];
  const float* W1d = (const float*)d_in[5];
  const float* b1d = (const float*)d_in[6];
  const float* sc1 = (const float*)d_in[7];
  const float* W2u = (const float*)d_in[8];
  const float* b2u = (const float*)d_in[9];
  const float* W2g = (const float*)d_in[10];
  const float* b2g = (const float*)d_in[11];
  const float* W2d = (const float*)d_in[12];
  const float* b2d = (const float*)d_in[13];
  const float* sc2 = (const float*)d_in[14];
  float* out = (float*)d_out;

  unsigned short* xt2  = (unsigned short*)d_ws;          // 2 MB [t][b][f] bf16
  unsigned short* part = xt2 + (size_t)1048576;          // 8 MB [512][64][128] bf16

  mlp_main<1><<<512, 512, 0, stream>>>(x,   W1u, b1u, W1g, b1g, W1d, part);
  finish1<<<256, 256, 0, stream>>>(part, x, b1d, sc1, xt2);
  mlp_main<0><<<512, 512, 0, stream>>>(xt2, W2u, b2u, W2g, b2g, W2d, part);
  finish2<<<256, 256, 0, stream>>>(part, xt2, b2d, sc2, out);
}

// Round 14
// 59.726 us; speedup vs baseline: 1.1362x; 1.1362x over previous
//
#include <hip/hip_runtime.h>

typedef __bf16 bf16x8 __attribute__((ext_vector_type(8)));
typedef float f32x4 __attribute__((ext_vector_type(4)));
typedef unsigned int uint;

#define XA_STR 152   // shorts; 304B rows, 16B-aligned

union Frag { __bf16 b[8]; bf16x8 v; unsigned short u[8]; };

__device__ __forceinline__ unsigned short bfbits(float f) {
  union { __bf16 h; unsigned short s; } c; c.h = (__bf16)f; return c.s;
}
__device__ __forceinline__ float bf2f(unsigned short h) {
  return __uint_as_float(((uint)h) << 16);
}

#define GL1(dst, voff, base, IMM) \
  asm volatile("global_load_dword %0, %1, %2 offset:" #IMM : "=v"(dst) : "v"(voff), "s"(base))
#define GL4(dst, voff, base) \
  asm volatile("global_load_dwordx4 %0, %1, %2" : "=v"(dst) : "v"(voff), "s"(base))
#define WAITV(N) do { asm volatile("s_waitcnt vmcnt(" #N ")" ::: "memory"); \
  __builtin_amdgcn_sched_barrier(0); } while (0)
#define BARX() asm volatile("s_waitcnt lgkmcnt(0)\n\ts_barrier" ::: "memory")

// dst[s][b][f] (bf16) = src[b][f][s]   (B=64, F=128, S=128), fp32 src
__global__ __launch_bounds__(256) void transpose_in(const float* __restrict__ src,
                                                    unsigned short* __restrict__ dst) {
  __shared__ unsigned short tile[64][68];
  const int b  = blockIdx.x >> 2;
  const int f0 = ((blockIdx.x >> 1) & 1) * 64;
  const int s0 = (blockIdx.x & 1) * 64;
  const int j = threadIdx.x & 63, i0 = threadIdx.x >> 6;
  const float* sp = src + b * 16384 + f0 * 128 + s0 + j;
#pragma unroll
  for (int p = 0; p < 16; ++p) {
    const int i = i0 + p * 4;
    tile[i][j] = bfbits(sp[i * 128]);
  }
  __syncthreads();
  unsigned short* dp = dst + s0 * 8192 + b * 128 + f0 + j;
#pragma unroll
  for (int p = 0; p < 16; ++p) {
    const int i = i0 + p * 4;
    dp[(size_t)i * 8192] = tile[j][i];
  }
}

// Block = (slot s, E-quarter q): 512 threads = 8 waves; wave owns 16 weight
// cols. R12 wave-private structure, but staging via WIDTH-16 global_load_lds
// (2 instructions per 2KB slice instead of 8). Slice layout: [32 rows][16
// floats] row-major; source pre-swizzled chunk ^= (row>>2)&3, same XOR on
// the read side. Wave-local counted-vmcnt ladder, no mid-stream barriers.
__global__ __launch_bounds__(512, 4) void mlp_main(
    const unsigned short* __restrict__ Xt,   // [128][64][128] bf16
    const float* __restrict__ Wu, const float* __restrict__ bu,
    const float* __restrict__ Wg, const float* __restrict__ bg,
    const float* __restrict__ Wd,
    unsigned short* __restrict__ partial)    // [512][64][128] bf16
{
  const int bid = blockIdx.x;
  const int s = bid >> 2, q = bid & 3;
  const int tid = threadIdx.x;
  const int wv = tid >> 6, lane = tid & 63;
  const int l16 = lane & 15, lg = lane >> 4;
  const int col = wv * 16 + l16;

  __shared__ __align__(16) float wsl[8][3][512];           // 48KB: per-wave ring
  __shared__ __align__(16) unsigned short xa[64 * XA_STR]; // X then A2 (19KB)

  const float* WuS = Wu + (size_t)s * 65536 + q * 128 + wv * 16;  // row 512f
  const float* WgS = Wg + (size_t)s * 65536 + q * 128 + wv * 16;
  const float* WdS = Wd + (size_t)s * 65536 + (size_t)q * 16384 + wv * 16; // row 128f

  // width-16 staging: lane ln covers row r=ln>>2 (+16*inst), chunk c=ln&3,
  // source-swizzled c' = c ^ ((r>>2)&3) = c ^ ((ln>>4)&3)
  const int rsw = lane >> 2;
  const int csw = ((lane & 3) ^ ((lane >> 4) & 3)) * 4;
  const int vswu = rsw * 512 + csw;   // up/gate per-lane float offset
  const int vswd = rsw * 128 + csw;   // down per-lane float offset

  float* const WA = &wsl[wv][0][0];
  float* const WB = &wsl[wv][1][0];
  float* const WC = &wsl[wv][2][0];

#define ISSW(BASE, VOFF, RS, SLOT) do { \
  asm volatile("s_waitcnt lgkmcnt(0)" ::: "memory"); \
  __builtin_amdgcn_sched_barrier(0); \
  __builtin_amdgcn_global_load_lds( \
    (const __attribute__((address_space(1))) void*)((BASE) + (VOFF)), \
    (__attribute__((address_space(3))) void*)(SLOT), 16, 0, 0); \
  __builtin_amdgcn_global_load_lds( \
    (const __attribute__((address_space(1))) void*)((BASE) + 16 * (RS) + (VOFF)), \
    (__attribute__((address_space(3))) void*)((SLOT) + 256), 16, 0, 0); \
} while (0)

  // read element (r=lg*8+j, col l16): word = r*16 + ((c ^ s(r))<<2) + e
#define BS(SLOT, FR) do { \
  _Pragma("unroll") for (int j = 0; j < 8; ++j) { \
    const int rr = lg * 8 + j; \
    FR.b[j] = (__bf16)(SLOT)[rr * 16 + \
      ((((l16 >> 2) ^ ((rr >> 2) & 3)) << 2) | (l16 & 3))]; \
  } \
} while (0)

  Frag a[4];
#define LOADA(KK) do { \
  _Pragma("unroll") \
  for (int mt = 0; mt < 4; ++mt) \
    a[mt].v = *(const bf16x8*)&xa[(mt * 16 + l16) * XA_STR + (((KK) * 4 + lg) << 3)]; \
} while (0)

  f32x4 au[4] = {}, ag[4] = {}, ad[4] = {};
#define MFMA4(FR, ACC) do { \
  _Pragma("unroll") \
  for (int mt = 0; mt < 4; ++mt) \
    ACC[mt] = __builtin_amdgcn_mfma_f32_16x16x32_bf16(a[mt].v, FR.v, ACC[mt], 0, 0, 0); \
} while (0)

  // ---- prologue: X + biases (asm-pinned), then 3 slices ----
  float buv, bgv;
  f32x4 xq0, xq1;
  const uint vbo = (uint)((q * 128 + col) * 4);
  const uint vx0 = (uint)(tid * 16), vx1 = vx0 + 8192;
  GL4(xq0, vx0, Xt + (size_t)s * 8192);
  GL4(xq1, vx1, Xt + (size_t)s * 8192);
  GL1(buv, vbo, bu + s * 512, 0);
  GL1(bgv, vbo, bg + s * 512, 0);
  ISSW(WuS,         vswu, 512, WA);      // slice0 = u0
  ISSW(WgS,         vswu, 512, WB);      // slice1 = g0
  ISSW(WuS + 16384, vswu, 512, WC);      // slice2 = u1

  WAITV(6);                              // X + biases arrived; 3 slices out
  {
    const int m0 = tid >> 4, ch0 = tid & 15;
    *(f32x4*)&xa[m0 * XA_STR + (ch0 << 3)] = xq0;
    const int p1 = tid + 512, m1 = p1 >> 4, ch1 = p1 & 15;
    *(f32x4*)&xa[m1 * XA_STR + (ch1 << 3)] = xq1;
  }
  BARX();                                // xa visible           [barrier 1]

  // ---- up/gate: 8 slices, wave-local ladder, no barriers ----
  Frag f;
  WAITV(4); LOADA(0); BS(WA, f); ISSW(WgS + 16384, vswu, 512, WA); MFMA4(f, au); // u0; g1->A
  WAITV(4);           BS(WB, f); ISSW(WuS + 32768, vswu, 512, WB); MFMA4(f, ag); // g0; u2->B
  WAITV(4); LOADA(1); BS(WC, f); ISSW(WgS + 32768, vswu, 512, WC); MFMA4(f, au); // u1; g2->C
  WAITV(4);           BS(WA, f); ISSW(WuS + 49152, vswu, 512, WA); MFMA4(f, ag); // g1; u3->A
  WAITV(4); LOADA(2); BS(WB, f); ISSW(WgS + 49152, vswu, 512, WB); MFMA4(f, au); // u2; g3->B
  WAITV(4);           BS(WC, f); ISSW(WdS,         vswd, 128, WC); MFMA4(f, ag); // g2; d0->C
  WAITV(4); LOADA(3); BS(WA, f); ISSW(WdS +  4096, vswd, 128, WA); MFMA4(f, au); // u3; d1->A
  WAITV(4);           BS(WB, f); ISSW(WdS +  8192, vswd, 128, WB); MFMA4(f, ag); // g3; d2->B

  // ---- silu epilogue -> A2 into xa ----
  float a2v[4][4];
#pragma unroll
  for (int mt = 0; mt < 4; ++mt)
#pragma unroll
    for (int r = 0; r < 4; ++r) {
      const float uv = au[mt][r] + buv;
      const float gv = ag[mt][r] + bgv;
      a2v[mt][r] = uv * (gv / (1.f + __expf(-gv)));
    }
  BARX();                                // all waves done reading X [barrier 2]
#pragma unroll
  for (int mt = 0; mt < 4; ++mt)
#pragma unroll
    for (int r = 0; r < 4; ++r)
      xa[(mt * 16 + lg * 4 + r) * XA_STR + col] = bfbits(a2v[mt][r]);
  BARX();                                // A2 visible               [barrier 3]

  // ---- down: 4 slices ----
  WAITV(4); LOADA(0); BS(WC, f); ISSW(WdS + 12288, vswd, 128, WC); MFMA4(f, ad); // d0; d3->C
  WAITV(4); LOADA(1); BS(WA, f); MFMA4(f, ad);                                   // d1
  WAITV(2); LOADA(2); BS(WB, f); MFMA4(f, ad);                                   // d2
  WAITV(0); LOADA(3); BS(WC, f); MFMA4(f, ad);                                   // d3

  unsigned short* po = partial + (size_t)bid * 8192;
#pragma unroll
  for (int mt = 0; mt < 4; ++mt)
#pragma unroll
    for (int r = 0; r < 4; ++r)
      po[(mt * 16 + lg * 4 + r) * 128 + col] = bfbits(ad[mt][r]);

#undef ISSW
#undef BS
#undef LOADA
#undef MFMA4
}

// Layer-1 finish, b-major, fused transpose-out -> xt2[d][b][s]
__global__ __launch_bounds__(256) void finish1(
    const unsigned short* __restrict__ part, const unsigned short* __restrict__ xt1,
    const float* __restrict__ bd, const float* __restrict__ scale,
    unsigned short* __restrict__ xt2)
{
  const int b = blockIdx.x >> 2, sq = blockIdx.x & 3;
  const int wvt = threadIdx.x >> 6, lane = threadIdx.x & 63;
  const int d0 = lane * 2;
  const float sc0 = scale[d0], sc1 = scale[d0 + 1];
  __shared__ unsigned short zt[128][40];

  for (int i = 0; i < 8; ++i) {
    const int sl = i * 4 + wvt;
    const int s = sq * 32 + sl;
    const uint rx = *(const uint*)(xt1 + (size_t)s * 8192 + b * 128 + d0);
    float z0 = bd[s * 128 + d0]     + bf2f((unsigned short)rx);
    float z1 = bd[s * 128 + d0 + 1] + bf2f((unsigned short)(rx >> 16));
#pragma unroll
    for (int p = 0; p < 4; ++p) {
      const uint rp = *(const uint*)(part + ((size_t)(s * 4 + p)) * 8192 + b * 128 + d0);
      z0 += bf2f((unsigned short)rp);
      z1 += bf2f((unsigned short)(rp >> 16));
    }
    float ss = z0 * z0 + z1 * z1;
#pragma unroll
    for (int off = 32; off; off >>= 1) ss += __shfl_xor(ss, off);
    const float inv = rsqrtf(ss * (1.f / 128.f) + 1e-5f);
    zt[d0][sl]     = bfbits(z0 * inv * sc0);
    zt[d0 + 1][sl] = bfbits(z1 * inv * sc1);
  }
  __syncthreads();
  const int dd = threadIdx.x >> 1, so = (threadIdx.x & 1) * 16;
  unsigned short* dst = xt2 + (size_t)dd * 8192 + b * 128 + sq * 32 + so;
  const uint4* srcv = (const uint4*)&zt[dd][so];
  ((uint4*)dst)[0] = srcv[0];
  ((uint4*)dst)[1] = srcv[1];
}

// Layer-2 finish, b-major: writes out[b][t][j] fp32 coalesced.
__global__ __launch_bounds__(256) void finish2(
    const unsigned short* __restrict__ part, const unsigned short* __restrict__ xt2,
    const float* __restrict__ bd, const float* __restrict__ scale,
    float* __restrict__ out)
{
  const int b = blockIdx.x >> 2, sq = blockIdx.x & 3;
  const int wvt = threadIdx.x >> 6, lane = threadIdx.x & 63;
  const int d0 = lane * 2;
  const float sc0 = scale[d0], sc1 = scale[d0 + 1];
  for (int i = 0; i < 8; ++i) {
    const int s = sq * 32 + i * 4 + wvt;
    const uint rx = *(const uint*)(xt2 + (size_t)s * 8192 + b * 128 + d0);
    float z0 = bd[s * 128 + d0]     + bf2f((unsigned short)rx);
    float z1 = bd[s * 128 + d0 + 1] + bf2f((unsigned short)(rx >> 16));
#pragma unroll
    for (int p = 0; p < 4; ++p) {
      const uint rp = *(const uint*)(part + ((size_t)(s * 4 + p)) * 8192 + b * 128 + d0);
      z0 += bf2f((unsigned short)rp);
      z1 += bf2f((unsigned short)(rp >> 16));
    }
    float ss = z0 * z0 + z1 * z1;
#pragma unroll
    for (int off = 32; off; off >>= 1) ss += __shfl_xor(ss, off);
    const float inv = rsqrtf(ss * (1.f / 128.f) + 1e-5f);
    *(float2*)(out + (size_t)b * 16384 + s * 128 + d0) =
        make_float2(z0 * inv * sc0, z1 * inv * sc1);
  }
}

extern "C" void kernel_launch(void* const* d_in, const int* in_sizes, int n_in,
                              void* d_out, int out_size, void* d_ws, size_t ws_size,
                              hipStream_t stream) {
  (void)in_sizes; (void)n_in; (void)out_size; (void)ws_size;
  const float* x   = (const float*)d_in[0];
  const float* W1u = (const float*)d_in[1];
  const float* b1u = (const float*)d_in[2];
  const float* W1g = (const float*)d_in[3];
  const float* b1g = (const float*)d_in[4];
  const float* W1d = (const float*)d_in[5];
  const float* b1d = (const float*)d_in[6];
  const float* sc1 = (const float*)d_in[7];
  const float* W2u = (const float*)d_in[8];
  const float* b2u = (const float*)d_in[9];
  const float* W2g = (const float*)d_in[10];
  const float* b2g = (const float*)d_in[11];
  const float* W2d = (const float*)d_in[12];
  const float* b2d = (const float*)d_in[13];
  const float* sc2 = (const float*)d_in[14];
  float* out = (float*)d_out;

  unsigned short* xt1  = (unsigned short*)d_ws;          // 2 MB [s][b][f] bf16
  unsigned short* xt2  = xt1 + (size_t)1048576;          // 2 MB [t][b][f] bf16
  unsigned short* part = xt2 + (size_t)1048576;          // 8 MB [512][64][128] bf16

  transpose_in<<<256, 256, 0, stream>>>(x, xt1);
  mlp_main<<<512, 512, 0, stream>>>(xt1, W1u, b1u, W1g, b1g, W1d, part);
  finish1<<<256, 256, 0, stream>>>(part, xt1, b1d, sc1, xt2);
  mlp_main<<<512, 512, 0, stream>>>(xt2, W2u, b2u, W2g, b2g, W2d, part);
  finish2<<<256, 256, 0, stream>>>(part, xt2, b2d, sc2, out);
}